// Round 1
// baseline (1111.793 us; speedup 1.0000x reference)
//
#include <hip/hip_runtime.h>
#include <hip/hip_bf16.h>
#include <cstddef>

// Problem constants (match reference)
constexpr int cB = 2;
constexpr int cN = 4096;
constexpr int cDIM = 512;
constexpr int cH = 8;
constexpr int cD = 64;
constexpr int cM = 256;
constexpr int cL = 16;          // N / M tokens per landmark
constexpr int cBH = cB * cH;    // 16
constexpr float cSCALE = 0.125f; // DHEAD^-0.5

// ---------------------------------------------------------------------------
// Generic fp32 tiled GEMM: C = alpha * A @ op(B) (+bias)
// A: Md x Kd (row pitch lda), B: NN -> Kd x Nd (ldb) / NT -> Nd x Kd (ldb)
// batching via blockIdx.z: batch = z / nsplit, split = z % nsplit
// offsets: base + batch*bs? + split*ks?   (split-K support for deep GEMMs)
// ---------------------------------------------------------------------------
template<int BM, int BN, int BK, int TM, int TN, bool TRANSB>
__global__ __launch_bounds__(256) void sgemm_k(
    const float* __restrict__ Ag, const float* __restrict__ Bg,
    float* __restrict__ Cg,
    int Md, int Nd, int Kd, int lda, int ldb, int ldc,
    long bsA, long bsB, long bsC,
    int nsplit, long ksA, long ksB, long ksC,
    float alpha, const float* __restrict__ bias)
{
  constexpr int TX = BN / TN;
  constexpr int TY = BM / TM;
  static_assert(TX * TY == 256, "block mismatch");
  constexpr int KQ = BK / 4;

  __shared__ float As[BK][BM + 4];
  __shared__ float Bs[BK][BN + 4];

  const int bz = blockIdx.z;
  const int batch = bz / nsplit;
  const int split = bz - batch * nsplit;
  const float* A  = Ag + (long)batch * bsA + (long)split * ksA;
  const float* Bp = Bg + (long)batch * bsB + (long)split * ksB;
  float* C        = Cg + (long)batch * bsC + (long)split * ksC;

  const int row0 = blockIdx.y * BM;
  const int col0 = blockIdx.x * BN;
  const int tid = threadIdx.x;
  const int tx = tid % TX;
  const int ty = tid / TX;

  float acc[TM][TN];
#pragma unroll
  for (int i = 0; i < TM; ++i)
#pragma unroll
    for (int j = 0; j < TN; ++j) acc[i][j] = 0.f;

  for (int k0 = 0; k0 < Kd; k0 += BK) {
    // ---- A tile (BM x BK), store transposed As[k][m]
#pragma unroll
    for (int it = 0; it < (BM * KQ) / 256; ++it) {
      int idx = tid + it * 256;
      int r = idx / KQ;
      int kq = idx - r * KQ;
      const float4 val = *reinterpret_cast<const float4*>(
          A + (long)(row0 + r) * lda + k0 + kq * 4);
      As[kq * 4 + 0][r] = val.x;
      As[kq * 4 + 1][r] = val.y;
      As[kq * 4 + 2][r] = val.z;
      As[kq * 4 + 3][r] = val.w;
    }
    // ---- B tile -> Bs[k][n]
    if (TRANSB) {
#pragma unroll
      for (int it = 0; it < (BN * KQ) / 256; ++it) {
        int idx = tid + it * 256;
        int r = idx / KQ;            // output-column index
        int kq = idx - r * KQ;
        const float4 val = *reinterpret_cast<const float4*>(
            Bp + (long)(col0 + r) * ldb + k0 + kq * 4);
        Bs[kq * 4 + 0][r] = val.x;
        Bs[kq * 4 + 1][r] = val.y;
        Bs[kq * 4 + 2][r] = val.z;
        Bs[kq * 4 + 3][r] = val.w;
      }
    } else {
#pragma unroll
      for (int it = 0; it < (BK * (BN / 4)) / 256; ++it) {
        int idx = tid + it * 256;
        int kk = idx / (BN / 4);
        int cq = idx - kk * (BN / 4);
        const float4 val = *reinterpret_cast<const float4*>(
            Bp + (long)(k0 + kk) * ldb + col0 + cq * 4);
        Bs[kk][cq * 4 + 0] = val.x;
        Bs[kk][cq * 4 + 1] = val.y;
        Bs[kk][cq * 4 + 2] = val.z;
        Bs[kk][cq * 4 + 3] = val.w;
      }
    }
    __syncthreads();
#pragma unroll
    for (int k = 0; k < BK; ++k) {
      float av[TM], bv[TN];
#pragma unroll
      for (int i = 0; i < TM; ++i) av[i] = As[k][ty * TM + i];
#pragma unroll
      for (int j = 0; j < TN; ++j) bv[j] = Bs[k][tx * TN + j];
#pragma unroll
      for (int i = 0; i < TM; ++i)
#pragma unroll
        for (int j = 0; j < TN; ++j) acc[i][j] += av[i] * bv[j];
    }
    __syncthreads();
  }

#pragma unroll
  for (int i = 0; i < TM; ++i) {
    const long r = row0 + ty * TM + i;
#pragma unroll
    for (int j = 0; j < TN; j += 4) {
      const int c = col0 + tx * TN + j;
      float4 o;
      o.x = acc[i][j + 0] * alpha;
      o.y = acc[i][j + 1] * alpha;
      o.z = acc[i][j + 2] * alpha;
      o.w = acc[i][j + 3] * alpha;
      if (bias) {
        o.x += bias[c + 0]; o.y += bias[c + 1];
        o.z += bias[c + 2]; o.w += bias[c + 3];
      }
      *reinterpret_cast<float4*>(C + r * ldc + c) = o;
    }
  }
}

// ---------------------------------------------------------------------------
// qkv [B,N,1536] -> q,k,v [B,H,N,D] with q *= SCALE
// ---------------------------------------------------------------------------
__global__ __launch_bounds__(256) void qkv_split_k(
    const float* __restrict__ qkv, float* __restrict__ q,
    float* __restrict__ k, float* __restrict__ v)
{
  long idx = (long)blockIdx.x * 256 + threadIdx.x; // over cBH*cN*cD = 2^22
  int d = idx & 63;
  int n = (int)((idx >> 6) & (cN - 1));
  int h = (int)((idx >> 18) & 7);
  int b = (int)(idx >> 21);
  long s = ((long)b * cN + n) * (3 * cH * cD) + h * cD + d;
  q[idx] = qkv[s] * cSCALE;
  k[idx] = qkv[s + 512];
  v[idx] = qkv[s + 1024];
}

// landmark mean-pool: dst[bh,m,d] = mean_{i<16} src[bh, m*16+i, d]
__global__ __launch_bounds__(256) void land_k(
    const float* __restrict__ src, float* __restrict__ dst)
{
  int idx = blockIdx.x * 256 + threadIdx.x;  // cBH*cM*cD = 262144
  int d = idx & 63;
  int m = (idx >> 6) & (cM - 1);
  int bh = idx >> 14;
  const float* p = src + ((long)bh * cN + (long)m * cL) * cD + d;
  float s = 0.f;
#pragma unroll
  for (int i = 0; i < cL; ++i) s += p[i * cD];
  dst[idx] = s * (1.f / cL);
}

// row softmax, one wave per row, whole row held in registers
template<int RLEN>
__global__ __launch_bounds__(256) void softmax_k(float* __restrict__ X)
{
  int row = blockIdx.x * 4 + (threadIdx.x >> 6);
  int lane = threadIdx.x & 63;
  float4* p = reinterpret_cast<float4*>(X + (long)row * RLEN);
  constexpr int NV = RLEN / 256;
  float4 v[NV];
  float mx = -3.4e38f;
#pragma unroll
  for (int i = 0; i < NV; ++i) {
    v[i] = p[(long)i * 64 + lane];
    mx = fmaxf(mx, fmaxf(fmaxf(v[i].x, v[i].y), fmaxf(v[i].z, v[i].w)));
  }
#pragma unroll
  for (int o = 32; o > 0; o >>= 1) mx = fmaxf(mx, __shfl_xor(mx, o));
  float s = 0.f;
#pragma unroll
  for (int i = 0; i < NV; ++i) {
    v[i].x = __expf(v[i].x - mx);
    v[i].y = __expf(v[i].y - mx);
    v[i].z = __expf(v[i].z - mx);
    v[i].w = __expf(v[i].w - mx);
    s += v[i].x + v[i].y + v[i].z + v[i].w;
  }
#pragma unroll
  for (int o = 32; o > 0; o >>= 1) s += __shfl_xor(s, o);
  float inv = 1.0f / s;
#pragma unroll
  for (int i = 0; i < NV; ++i) {
    v[i].x *= inv; v[i].y *= inv; v[i].z *= inv; v[i].w *= inv;
    p[(long)i * 64 + lane] = v[i];
  }
}

// per-matrix max row-sum / max col-sum of |a| (reference takes GLOBAL max later)
__global__ __launch_bounds__(256) void pinv_prep_k(
    const float* __restrict__ a, float* __restrict__ mx)
{
  const int bh = blockIdx.x;
  const float* A = a + (long)bh * cM * cM;
  const int t = threadIdx.x;
  float rs = 0.f, cs = 0.f;
  for (int c2 = 0; c2 < cM; ++c2) rs += fabsf(A[(long)t * cM + c2]);
  for (int r = 0; r < cM; ++r) cs += fabsf(A[(long)r * cM + t]);
  __shared__ float red[256];
  red[t] = rs; __syncthreads();
  for (int s = 128; s > 0; s >>= 1) {
    if (t < s) red[t] = fmaxf(red[t], red[t + s]);
    __syncthreads();
  }
  float maxr = red[0]; __syncthreads();
  red[t] = cs; __syncthreads();
  for (int s = 128; s > 0; s >>= 1) {
    if (t < s) red[t] = fmaxf(red[t], red[t + s]);
    __syncthreads();
  }
  if (t == 0) { mx[2 * bh] = maxr; mx[2 * bh + 1] = red[0]; }
}

// z = a^T * 1/(globalmax_rowsum * globalmax_colsum), 32x32 LDS transpose
__global__ __launch_bounds__(256) void pinv_init_k(
    const float* __restrict__ a, const float* __restrict__ mx,
    float* __restrict__ z)
{
  float mr = 0.f, mc = 0.f;
#pragma unroll
  for (int i = 0; i < cBH; ++i) {
    mr = fmaxf(mr, mx[2 * i]);
    mc = fmaxf(mc, mx[2 * i + 1]);
  }
  const float scale = 1.0f / (mr * mc);
  __shared__ float tile[32][33];
  int bh = blockIdx.z;
  const float* A = a + (long)bh * cM * cM;
  float* Z = z + (long)bh * cM * cM;
  int c0 = blockIdx.x * 32, r0 = blockIdx.y * 32;
  int tx = threadIdx.x & 31, ty = threadIdx.x >> 5; // 32 x 8
#pragma unroll
  for (int i = 0; i < 32; i += 8)
    tile[ty + i][tx] = A[(long)(r0 + ty + i) * cM + c0 + tx];
  __syncthreads();
#pragma unroll
  for (int i = 0; i < 32; i += 8)
    Z[(long)(c0 + ty + i) * cM + r0 + tx] = tile[tx][ty + i] * scale;
}

// Y = c*I - X  (batched 256x256)
__global__ __launch_bounds__(256) void diag_k(
    const float* __restrict__ X, float* __restrict__ Y, float c)
{
  int idx = blockIdx.x * 256 + threadIdx.x;  // cBH*cM*cM = 1048576
  int col = idx & 255, row = (idx >> 8) & 255;
  float val = -X[idx];
  if (row == col) val += c;
  Y[idx] = val;
}

// reduce split-K partials: t3 = sum_{s<8} part[bh*8+s]
__global__ __launch_bounds__(256) void reduce8_k(
    const float* __restrict__ part, float* __restrict__ t3)
{
  int idx = blockIdx.x * 256 + threadIdx.x;  // cBH*cM*cD
  int bh = idx >> 14;
  int inner = idx & 16383;
  float s = 0.f;
#pragma unroll
  for (int i = 0; i < 8; ++i) s += part[((long)bh * 8 + i) * 16384 + inner];
  t3[idx] = s;
}

// grouped conv residual over head axis (SAME pad 33 -> taps kh in [9,23]),
// accumulates into outh [B,H,N,D]
__global__ __launch_bounds__(256) void conv_k(
    const float* __restrict__ v, const float* __restrict__ cw,
    float* __restrict__ outh)
{
  __shared__ float wsm[15][8][64];  // taps kh=9..23
  for (int i = threadIdx.x; i < 15 * 512; i += 256) {
    int kh = i >> 9;
    int rem = i & 511;
    wsm[kh][rem >> 6][rem & 63] = cw[(kh + 9) * 512 + rem];
  }
  __syncthreads();
  int oc = threadIdx.x & 63;
  int nl = threadIdx.x >> 6;
  int b = blockIdx.y;
  long n = (long)blockIdx.x * 4 + nl;
  int g = oc >> 3;
  float vv[8][8];
#pragma unroll
  for (int j = 0; j < 8; ++j)
#pragma unroll
    for (int ic = 0; ic < 8; ++ic)
      vv[j][ic] = v[(((long)(b * 8 + j)) * cN + n) * 64 + g * 8 + ic];
#pragma unroll
  for (int i = 0; i < 8; ++i) {
    float s = 0.f;
#pragma unroll
    for (int j = 0; j < 8; ++j) {
      int kh2 = j - i + 7;   // (j-i+16)-9 in [0,14]
#pragma unroll
      for (int ic = 0; ic < 8; ++ic) s += vv[j][ic] * wsm[kh2][ic][oc];
    }
    outh[(((long)(b * 8 + i)) * cN + n) * 64 + oc] += s;
  }
}

// [B,H,N,D] -> [B,N,H*D]
__global__ __launch_bounds__(256) void rows_k(
    const float* __restrict__ outh, float* __restrict__ xo)
{
  long idx = (long)blockIdx.x * 256 + threadIdx.x;  // cB*cN*cDIM = 2^22
  int c2 = (int)(idx & 511);
  int n = (int)((idx >> 9) & (cN - 1));
  int b = (int)(idx >> 21);
  int h = c2 >> 6, d = c2 & 63;
  xo[idx] = outh[(((long)(b * 8 + h)) * cN + n) * 64 + d];
}

// ---------------------------------------------------------------------------
extern "C" void kernel_launch(void* const* d_in, const int* in_sizes, int n_in,
                              void* d_out, int out_size, void* d_ws, size_t ws_size,
                              hipStream_t stream)
{
  const float* x     = (const float*)d_in[0];
  const float* w_qkv = (const float*)d_in[1];
  const float* w_out = (const float*)d_in[2];
  const float* b_out = (const float*)d_in[3];
  const float* cw    = (const float*)d_in[4];
  float* out = (float*)d_out;

  // workspace carve-up (~235 MB fp32)
  float* ws = (float*)d_ws;
  size_t off = 0;
  auto alloc = [&](size_t nelem) {
    float* p = ws + off;
    off += (nelem + 3) & ~(size_t)3;
    return p;
  };
  float* q     = alloc((size_t)cBH * cN * cD);
  float* kk    = alloc((size_t)cBH * cN * cD);
  float* v     = alloc((size_t)cBH * cN * cD);
  float* attn1 = alloc((size_t)cBH * cN * cM);   // doubles as qkv tmp
  float* attn3 = alloc((size_t)cBH * cM * cN);   // doubles as xo
  float* attn2 = alloc((size_t)cBH * cM * cM);
  float* zb    = alloc((size_t)cBH * cM * cM);
  float* azb   = alloc((size_t)cBH * cM * cM);
  float* ub    = alloc((size_t)cBH * cM * cM);
  float* wb    = alloc((size_t)cBH * cM * cM);
  float* ql    = alloc((size_t)cBH * cM * cD);
  float* kl    = alloc((size_t)cBH * cM * cD);
  float* t3p   = alloc((size_t)cBH * 8 * cM * cD);
  float* t3    = alloc((size_t)cBH * cM * cD);
  float* t4    = alloc((size_t)cBH * cM * cD);
  float* outh  = alloc((size_t)cBH * cN * cD);
  float* mx    = alloc(64);
  float* qkv   = attn1;
  float* xo    = attn3;

  // 1) qkv = x @ w_qkv   [8192x512]@[512x1536]
  sgemm_k<128,128,16,8,8,false><<<dim3(1536/128, 8192/128, 1), 256, 0, stream>>>(
      x, w_qkv, qkv, cB*cN, 3*cH*cD, cDIM, cDIM, 3*cH*cD, 3*cH*cD,
      0, 0, 0, 1, 0, 0, 0, 1.f, nullptr);

  // 2) split into q (scaled), k, v  [B,H,N,D]
  qkv_split_k<<<(cBH * cN * cD) / 256, 256, 0, stream>>>(qkv, q, kk, v);

  // 3) landmarks
  land_k<<<(cBH * cM * cD) / 256, 256, 0, stream>>>(q, ql);
  land_k<<<(cBH * cM * cD) / 256, 256, 0, stream>>>(kk, kl);

  // 4) sim1 = q @ kl^T -> attn1 [4096x256] per bh
  sgemm_k<128,128,16,8,8,true><<<dim3(cM/128, cN/128, cBH), 256, 0, stream>>>(
      q, kl, attn1, cN, cM, cD, cD, cD, cM,
      (long)cN*cD, (long)cM*cD, (long)cN*cM, 1, 0, 0, 0, 1.f, nullptr);
  softmax_k<256><<<(cBH * cN) / 4, 256, 0, stream>>>(attn1);

  // 5) sim2 = ql @ kl^T -> attn2 [256x256]
  sgemm_k<64,64,16,4,4,true><<<dim3(cM/64, cM/64, cBH), 256, 0, stream>>>(
      ql, kl, attn2, cM, cM, cD, cD, cD, cM,
      (long)cM*cD, (long)cM*cD, (long)cM*cM, 1, 0, 0, 0, 1.f, nullptr);
  softmax_k<256><<<(cBH * cM) / 4, 256, 0, stream>>>(attn2);

  // 6) sim3 = ql @ k^T -> attn3 [256x4096]
  sgemm_k<128,128,16,8,8,true><<<dim3(cN/128, cM/128, cBH), 256, 0, stream>>>(
      ql, kk, attn3, cM, cN, cD, cD, cD, cN,
      (long)cM*cD, (long)cN*cD, (long)cM*cN, 1, 0, 0, 0, 1.f, nullptr);
  softmax_k<4096><<<(cBH * cM) / 4, 256, 0, stream>>>(attn3);

  // 7) pinv of attn2 (global-max scaled init + 6 Newton-Schulz iters)
  pinv_prep_k<<<cBH, 256, 0, stream>>>(attn2, mx);
  pinv_init_k<<<dim3(8, 8, cBH), 256, 0, stream>>>(attn2, mx, zb);

  float* zc = zb;
  float* wc = wb;
  for (int it = 0; it < 6; ++it) {
    // az = a @ z
    sgemm_k<64,64,16,4,4,false><<<dim3(4, 4, cBH), 256, 0, stream>>>(
        attn2, zc, azb, cM, cM, cM, cM, cM, cM,
        (long)cM*cM, (long)cM*cM, (long)cM*cM, 1, 0, 0, 0, 1.f, nullptr);
    diag_k<<<4096, 256, 0, stream>>>(azb, ub, 7.f);
    // w = az @ u
    sgemm_k<64,64,16,4,4,false><<<dim3(4, 4, cBH), 256, 0, stream>>>(
        azb, ub, wc, cM, cM, cM, cM, cM, cM,
        (long)cM*cM, (long)cM*cM, (long)cM*cM, 1, 0, 0, 0, 1.f, nullptr);
    diag_k<<<4096, 256, 0, stream>>>(wc, ub, 15.f);
    // w = az @ u
    sgemm_k<64,64,16,4,4,false><<<dim3(4, 4, cBH), 256, 0, stream>>>(
        azb, ub, wc, cM, cM, cM, cM, cM, cM,
        (long)cM*cM, (long)cM*cM, (long)cM*cM, 1, 0, 0, 0, 1.f, nullptr);
    diag_k<<<4096, 256, 0, stream>>>(wc, ub, 13.f);
    // z_new = 0.25 * z @ u  -> wc, then swap
    sgemm_k<64,64,16,4,4,false><<<dim3(4, 4, cBH), 256, 0, stream>>>(
        zc, ub, wc, cM, cM, cM, cM, cM, cM,
        (long)cM*cM, (long)cM*cM, (long)cM*cM, 1, 0, 0, 0, 0.25f, nullptr);
    float* t = zc; zc = wc; wc = t;
  }

  // 8) t3 = attn3 @ v  [256x4096]@[4096x64], split-K=8
  sgemm_k<64,64,16,4,4,false><<<dim3(1, cM/64, cBH * 8), 256, 0, stream>>>(
      attn3, v, t3p, cM, cD, cN / 8, cN, cD, cD,
      (long)cM*cN, (long)cN*cD, (long)8*cM*cD,
      8, (long)(cN / 8), (long)(cN / 8) * cD, (long)cM*cD, 1.f, nullptr);
  reduce8_k<<<(cBH * cM * cD) / 256, 256, 0, stream>>>(t3p, t3);

  // 9) t4 = z @ t3  [256x256]@[256x64]
  sgemm_k<64,64,16,4,4,false><<<dim3(1, cM/64, cBH), 256, 0, stream>>>(
      zc, t3, t4, cM, cD, cM, cM, cD, cD,
      (long)cM*cM, (long)cM*cD, (long)cM*cD, 1, 0, 0, 0, 1.f, nullptr);

  // 10) outh = attn1 @ t4  [4096x256]@[256x64]
  sgemm_k<128,64,16,8,4,false><<<dim3(1, cN/128, cBH), 256, 0, stream>>>(
      attn1, t4, outh, cN, cD, cM, cM, cD, cD,
      (long)cN*cM, (long)cM*cD, (long)cN*cD, 1, 0, 0, 0, 1.f, nullptr);

  // 11) grouped-conv residual added into outh
  conv_k<<<dim3(cN / 4, cB), 256, 0, stream>>>(v, cw, outh);

  // 12) [B,H,N,D] -> [B,N,512]
  rows_k<<<(cB * cN * cDIM) / 256, 256, 0, stream>>>(outh, xo);

  // 13) out = xo @ w_out + b_out
  sgemm_k<128,128,16,8,8,false><<<dim3(cDIM/128, (cB*cN)/128, 1), 256, 0, stream>>>(
      xo, w_out, out, cB*cN, cDIM, cDIM, cDIM, cDIM, cDIM,
      0, 0, 0, 1, 0, 0, 0, 1.f, b_out);
}

// Round 10
// 677.694 us; speedup vs baseline: 1.6406x; 1.6406x over previous
//
#include <hip/hip_runtime.h>
#include <hip/hip_bf16.h>
#include <cstddef>

constexpr int cB = 2;
constexpr int cN = 4096;
constexpr int cDIM = 512;
constexpr int cH = 8;
constexpr int cD = 64;
constexpr int cM = 256;
constexpr int cL = 16;
constexpr int cBH = cB * cH;
constexpr float cSCALE = 0.125f;

// Guide-verified fragment types for mfma_f32_16x16x32_bf16 (cdna_hip §3):
// "using frag_ab = __attribute__((ext_vector_type(8))) short; // 8 bf16"
typedef short bf16x8_t __attribute__((ext_vector_type(8)));
typedef float f32x4_t __attribute__((ext_vector_type(4)));
typedef unsigned short u16x8_t __attribute__((ext_vector_type(8)));

// ---------------------------------------------------------------------------
// Stage a ROWS x 32 fp32 tile into split-bf16 hi/lo LDS tiles.
// LDS row stride 40 bf16 (80 B) -> 2-way-max bank aliasing on b128 frag reads.
// k-quartet permutation [0,4,1,5,2,6,3,7] makes the 8 bf16 an MFMA lane needs
// contiguous (single b128 read at byte offset 16*(lane>>4)).
// ---------------------------------------------------------------------------
template<int ROWS>
__device__ inline void stage_tile(const float* __restrict__ P, int ld, int k0,
                                  int tid, unsigned short* Xh, unsigned short* Xl)
{
#pragma unroll
  for (int it = 0; it < (ROWS * 8) / 256; ++it) {
    int idx = tid + it * 256;
    int r = idx >> 3, g = idx & 7;
    const float4 t = *reinterpret_cast<const float4*>(P + (long)r * ld + k0 + g * 4);
    int q = 2 * (g & 3) + (g >> 2);
    float xs[4] = {t.x, t.y, t.z, t.w};
    unsigned short hh[4], ll[4];
#pragma unroll
    for (int j = 0; j < 4; ++j) {
      unsigned int b = __float_as_uint(xs[j]);
      hh[j] = (unsigned short)(b >> 16);
      float hf = __uint_as_float(b & 0xFFFF0000u);
      ll[j] = (unsigned short)(__float_as_uint(xs[j] - hf) >> 16);
    }
    *reinterpret_cast<ushort4*>(&Xh[r * 40 + q * 4]) = make_ushort4(hh[0], hh[1], hh[2], hh[3]);
    *reinterpret_cast<ushort4*>(&Xl[r * 40 + q * 4]) = make_ushort4(ll[0], ll[1], ll[2], ll[3]);
  }
}

// ---------------------------------------------------------------------------
// Split-bf16 MFMA GEMM, NT form: result = alpha * A @ B^T
//   A: M x K rows (lda), B: N x K rows (ldb). 256 threads = 4 waves (WM x WN).
// Epilogue outputs (any may be null):
//   C  : alpha*AB^T (+bias[col])
//   CT : (alpha*AB^T)^T   (transposed store, float4 per lane)
//   C2 : diagc*I - alpha*AB^T
// Batch via blockIdx.z: batch = z/nsplit, split = z%nsplit (split-K support).
// ---------------------------------------------------------------------------
template<int BM, int BN, int WM, int WN>
__global__ __launch_bounds__(256) void mfma_nt_k(
    const float* __restrict__ Ag, const float* __restrict__ Bg,
    float* __restrict__ Cg, float* __restrict__ CTg, float* __restrict__ C2g,
    int Kd, int lda, int ldb, int ldc, int ldct,
    long bsA, long bsB, long bsC, long bsCT, long bsC2,
    int nsplit, long ksA, long ksB, long ksC,
    float alpha, float diagc, const float* __restrict__ bias)
{
  constexpr int FM = BM / (16 * WM);
  constexpr int FN = BN / (16 * WN);

  __shared__ unsigned short Ah[BM * 40];
  __shared__ unsigned short Al[BM * 40];
  __shared__ unsigned short Bh[BN * 40];
  __shared__ unsigned short Bl[BN * 40];

  const int bz = blockIdx.z;
  const int batch = bz / nsplit;
  const int split = bz - batch * nsplit;
  const float* A = Ag + (long)batch * bsA + (long)split * ksA;
  const float* B = Bg + (long)batch * bsB + (long)split * ksB;

  const int tid = threadIdx.x;
  const int wave = tid >> 6;
  const int lane = tid & 63;
  const int wm = wave & (WM - 1);
  const int wn = wave / WM;

  f32x4_t acc[FM][FN];
#pragma unroll
  for (int i = 0; i < FM; ++i)
#pragma unroll
    for (int j = 0; j < FN; ++j) acc[i][j] = (f32x4_t){0.f, 0.f, 0.f, 0.f};

  const int arow0 = (wm * FM * 16 + (lane & 15)) * 40 + (lane >> 4) * 8;
  const int brow0 = (wn * FN * 16 + (lane & 15)) * 40 + (lane >> 4) * 8;
  const long arowg = (long)blockIdx.y * BM;
  const long browg = (long)blockIdx.x * BN;

  for (int k0 = 0; k0 < Kd; k0 += 32) {
    stage_tile<BM>(A + arowg * lda, lda, k0, tid, Ah, Al);
    stage_tile<BN>(B + browg * ldb, ldb, k0, tid, Bh, Bl);
    __syncthreads();

    bf16x8_t ah[FM], al[FM], bh[FN], bl[FN];
#pragma unroll
    for (int mt = 0; mt < FM; ++mt) {
      ah[mt] = __builtin_bit_cast(bf16x8_t, *reinterpret_cast<const u16x8_t*>(&Ah[arow0 + mt * 16 * 40]));
      al[mt] = __builtin_bit_cast(bf16x8_t, *reinterpret_cast<const u16x8_t*>(&Al[arow0 + mt * 16 * 40]));
    }
#pragma unroll
    for (int nt = 0; nt < FN; ++nt) {
      bh[nt] = __builtin_bit_cast(bf16x8_t, *reinterpret_cast<const u16x8_t*>(&Bh[brow0 + nt * 16 * 40]));
      bl[nt] = __builtin_bit_cast(bf16x8_t, *reinterpret_cast<const u16x8_t*>(&Bl[brow0 + nt * 16 * 40]));
    }
#pragma unroll
    for (int mt = 0; mt < FM; ++mt)
#pragma unroll
      for (int nt = 0; nt < FN; ++nt) {
        acc[mt][nt] = __builtin_amdgcn_mfma_f32_16x16x32_bf16(ah[mt], bh[nt], acc[mt][nt], 0, 0, 0);
        acc[mt][nt] = __builtin_amdgcn_mfma_f32_16x16x32_bf16(ah[mt], bl[nt], acc[mt][nt], 0, 0, 0);
        acc[mt][nt] = __builtin_amdgcn_mfma_f32_16x16x32_bf16(al[mt], bh[nt], acc[mt][nt], 0, 0, 0);
      }
    __syncthreads();
  }

  float* Cp  = Cg  ? Cg  + (long)batch * bsC  + (long)split * ksC : nullptr;
  float* CTp = CTg ? CTg + (long)batch * bsCT : nullptr;
  float* C2p = C2g ? C2g + (long)batch * bsC2 : nullptr;

  const int rgrp = (lane >> 4) * 4;
  const int cidx = lane & 15;
#pragma unroll
  for (int mt = 0; mt < FM; ++mt) {
#pragma unroll
    for (int nt = 0; nt < FN; ++nt) {
      f32x4_t a = acc[mt][nt];
      const int rbase = (int)arowg + wm * FM * 16 + mt * 16 + rgrp;
      const int cglob = (int)browg + wn * FN * 16 + nt * 16 + cidx;
      if (Cp) {
        float bv = bias ? bias[cglob] : 0.f;
#pragma unroll
        for (int r = 0; r < 4; ++r)
          Cp[(long)(rbase + r) * ldc + cglob] = a[r] * alpha + bv;
      }
      if (C2p) {
#pragma unroll
        for (int r = 0; r < 4; ++r) {
          int rr = rbase + r;
          C2p[(long)rr * ldc + cglob] = (rr == cglob ? diagc : 0.f) - a[r] * alpha;
        }
      }
      if (CTp) {
        float4 o = {a[0] * alpha, a[1] * alpha, a[2] * alpha, a[3] * alpha};
        *reinterpret_cast<float4*>(&CTp[(long)cglob * ldct + rbase]) = o;
      }
    }
  }
}

// ---------------------------------------------------------------------------
__global__ __launch_bounds__(256) void trans_k(
    const float* __restrict__ src, float* __restrict__ dst,
    int R, int C, long ss, long ds)
{
  __shared__ float tile[32][33];
  const float* S = src + (long)blockIdx.z * ss;
  float* D = dst + (long)blockIdx.z * ds;
  int c0 = blockIdx.x * 32, r0 = blockIdx.y * 32;
  int tx = threadIdx.x & 31, ty = threadIdx.x >> 5;
#pragma unroll
  for (int i = 0; i < 32; i += 8)
    tile[ty + i][tx] = S[(long)(r0 + ty + i) * C + c0 + tx];
  __syncthreads();
#pragma unroll
  for (int i = 0; i < 32; i += 8)
    D[(long)(c0 + ty + i) * R + r0 + tx] = tile[tx][ty + i];
}

// qkv [B,N,1536] -> q (scaled), k, v  [B,H,N,D]
__global__ __launch_bounds__(256) void qkv_split_k(
    const float* __restrict__ qkv, float* __restrict__ q,
    float* __restrict__ k, float* __restrict__ v)
{
  long idx = (long)blockIdx.x * 256 + threadIdx.x;
  int d = idx & 63;
  int n = (int)((idx >> 6) & (cN - 1));
  int h = (int)((idx >> 18) & 7);
  int b = (int)(idx >> 21);
  long s = ((long)b * cN + n) * (3 * cH * cD) + h * cD + d;
  q[idx] = qkv[s] * cSCALE;
  k[idx] = qkv[s + 512];
  v[idx] = qkv[s + 1024];
}

__global__ __launch_bounds__(256) void land_k(
    const float* __restrict__ src, float* __restrict__ dst)
{
  int idx = blockIdx.x * 256 + threadIdx.x;
  int d = idx & 63;
  int m = (idx >> 6) & (cM - 1);
  int bh = idx >> 14;
  const float* p = src + ((long)bh * cN + (long)m * cL) * cD + d;
  float s = 0.f;
#pragma unroll
  for (int i = 0; i < cL; ++i) s += p[i * cD];
  dst[idx] = s * (1.f / cL);
}

template<int RLEN>
__global__ __launch_bounds__(256) void softmax_k(float* __restrict__ X)
{
  int row = blockIdx.x * 4 + (threadIdx.x >> 6);
  int lane = threadIdx.x & 63;
  float4* p = reinterpret_cast<float4*>(X + (long)row * RLEN);
  constexpr int NV = RLEN / 256;
  float4 v[NV];
  float mx = -3.4e38f;
#pragma unroll
  for (int i = 0; i < NV; ++i) {
    v[i] = p[(long)i * 64 + lane];
    mx = fmaxf(mx, fmaxf(fmaxf(v[i].x, v[i].y), fmaxf(v[i].z, v[i].w)));
  }
#pragma unroll
  for (int o = 32; o > 0; o >>= 1) mx = fmaxf(mx, __shfl_xor(mx, o));
  float s = 0.f;
#pragma unroll
  for (int i = 0; i < NV; ++i) {
    v[i].x = __expf(v[i].x - mx);
    v[i].y = __expf(v[i].y - mx);
    v[i].z = __expf(v[i].z - mx);
    v[i].w = __expf(v[i].w - mx);
    s += v[i].x + v[i].y + v[i].z + v[i].w;
  }
#pragma unroll
  for (int o = 32; o > 0; o >>= 1) s += __shfl_xor(s, o);
  float inv = 1.0f / s;
#pragma unroll
  for (int i = 0; i < NV; ++i) {
    v[i].x *= inv; v[i].y *= inv; v[i].z *= inv; v[i].w *= inv;
    p[(long)i * 64 + lane] = v[i];
  }
}

// per-matrix max |row-sum| / |col-sum| (global max taken in pinv_init2)
__global__ __launch_bounds__(256) void pinv_prep_k(
    const float* __restrict__ a, float* __restrict__ mx)
{
  const int bh = blockIdx.x;
  const float* A = a + (long)bh * cM * cM;
  const int t = threadIdx.x;
  float rs = 0.f, cs = 0.f;
  for (int c2 = 0; c2 < cM; ++c2) rs += fabsf(A[(long)t * cM + c2]);
  for (int r = 0; r < cM; ++r) cs += fabsf(A[(long)r * cM + t]);
  __shared__ float red[256];
  red[t] = rs; __syncthreads();
  for (int s = 128; s > 0; s >>= 1) {
    if (t < s) red[t] = fmaxf(red[t], red[t + s]);
    __syncthreads();
  }
  float maxr = red[0]; __syncthreads();
  red[t] = cs; __syncthreads();
  for (int s = 128; s > 0; s >>= 1) {
    if (t < s) red[t] = fmaxf(red[t], red[t + s]);
    __syncthreads();
  }
  if (t == 0) { mx[2 * bh] = maxr; mx[2 * bh + 1] = red[0]; }
}

// z0' = scale*a (plain), z0 = scale*a^T ; scale = 1/(gmax_rs * gmax_cs)
__global__ __launch_bounds__(256) void pinv_init2_k(
    const float* __restrict__ a, const float* __restrict__ mx,
    float* __restrict__ zp, float* __restrict__ zt)
{
  float mr = 0.f, mc = 0.f;
#pragma unroll
  for (int i = 0; i < cBH; ++i) {
    mr = fmaxf(mr, mx[2 * i]);
    mc = fmaxf(mc, mx[2 * i + 1]);
  }
  const float scale = 1.0f / (mr * mc);
  __shared__ float tile[32][33];
  int bh = blockIdx.z;
  const float* A = a + (long)bh * cM * cM;
  float* ZP = zp + (long)bh * cM * cM;
  float* ZT = zt + (long)bh * cM * cM;
  int c0 = blockIdx.x * 32, r0 = blockIdx.y * 32;
  int tx = threadIdx.x & 31, ty = threadIdx.x >> 5;
#pragma unroll
  for (int i = 0; i < 32; i += 8) {
    float val = A[(long)(r0 + ty + i) * cM + c0 + tx] * scale;
    tile[ty + i][tx] = val;
    ZP[(long)(r0 + ty + i) * cM + c0 + tx] = val;
  }
  __syncthreads();
#pragma unroll
  for (int i = 0; i < 32; i += 8)
    ZT[(long)(c0 + ty + i) * cM + r0 + tx] = tile[tx][ty + i];
}

// t3' = sum over 8 split-K partials
__global__ __launch_bounds__(256) void reduce8_k(
    const float* __restrict__ part, float* __restrict__ t3)
{
  int idx = blockIdx.x * 256 + threadIdx.x;   // cBH*cD*cM = 262144
  int bh = idx >> 14;
  int inner = idx & 16383;
  float s = 0.f;
#pragma unroll
  for (int i = 0; i < 8; ++i) s += part[((long)bh * 8 + i) * 16384 + inner];
  t3[idx] = s;
}

// grouped conv residual (SAME pad 33 over head axis -> taps kh in [9,23]),
// accumulates into outh [B,H,N,D]
__global__ __launch_bounds__(256) void conv_k(
    const float* __restrict__ v, const float* __restrict__ cw,
    float* __restrict__ outh)
{
  __shared__ float wsm[15][8][64];
  for (int i = threadIdx.x; i < 15 * 512; i += 256) {
    int kh = i >> 9;
    int rem = i & 511;
    wsm[kh][rem >> 6][rem & 63] = cw[(kh + 9) * 512 + rem];
  }
  __syncthreads();
  int oc = threadIdx.x & 63;
  int nl = threadIdx.x >> 6;
  int b = blockIdx.y;
  long n = (long)blockIdx.x * 4 + nl;
  int g = oc >> 3;
  float vv[8][8];
#pragma unroll
  for (int j = 0; j < 8; ++j)
#pragma unroll
    for (int ic = 0; ic < 8; ++ic)
      vv[j][ic] = v[(((long)(b * 8 + j)) * cN + n) * 64 + g * 8 + ic];
#pragma unroll
  for (int i = 0; i < 8; ++i) {
    float s = 0.f;
#pragma unroll
    for (int j = 0; j < 8; ++j) {
      int kh2 = j - i + 7;
#pragma unroll
      for (int ic = 0; ic < 8; ++ic) s += vv[j][ic] * wsm[kh2][ic][oc];
    }
    outh[(((long)(b * 8 + i)) * cN + n) * 64 + oc] += s;
  }
}

// [B,H,N,D] -> [B,N,H*D]
__global__ __launch_bounds__(256) void rows_k(
    const float* __restrict__ outh, float* __restrict__ xo)
{
  long idx = (long)blockIdx.x * 256 + threadIdx.x;
  int c2 = (int)(idx & 511);
  int n = (int)((idx >> 9) & (cN - 1));
  int b = (int)(idx >> 21);
  int h = c2 >> 6, d = c2 & 63;
  xo[idx] = outh[(((long)(b * 8 + h)) * cN + n) * 64 + d];
}

// ---------------------------------------------------------------------------
extern "C" void kernel_launch(void* const* d_in, const int* in_sizes, int n_in,
                              void* d_out, int out_size, void* d_ws, size_t ws_size,
                              hipStream_t stream)
{
  const float* x     = (const float*)d_in[0];
  const float* w_qkv = (const float*)d_in[1];
  const float* w_out = (const float*)d_in[2];
  const float* b_out = (const float*)d_in[3];
  const float* cw    = (const float*)d_in[4];
  float* out = (float*)d_out;

  float* ws = (float*)d_ws;
  size_t off = 0;
  auto alloc = [&](size_t nelem) {
    float* p = ws + off;
    off += (nelem + 3) & ~(size_t)3;
    return p;
  };
  float* attn1 = alloc((size_t)cBH * cN * cM);   // also qkv tmp (12.58M < 16.78M)
  float* attn3 = alloc((size_t)cBH * cM * cN);   // also xo after t3'-gemm
  float* q     = alloc((size_t)cBH * cN * cD);   // after sim1: az,u1,u2 / later t3p
  float* kbuf  = alloc((size_t)cBH * cN * cD);   // after sim3: zpA,zpB,ztA,ztB
  float* v     = alloc((size_t)cBH * cN * cD);
  float* vT    = alloc((size_t)cBH * cD * cN);   // outh aliases after t3'-gemm
  float* attn2 = alloc((size_t)cBH * cM * cM);
  float* ql    = alloc((size_t)cBH * cM * cD);
  float* kl    = alloc((size_t)cBH * cM * cD);
  float* t3t   = alloc((size_t)cBH * cD * cM);
  float* t4t   = alloc((size_t)cBH * cD * cM);
  float* wqT   = alloc((size_t)3 * cH * cD * cDIM);
  float* woT   = alloc((size_t)cDIM * cDIM);
  float* mx    = alloc(64);

  float* qkv = attn1;
  float* xo  = attn3;
  const long MM = (long)cM * cM;                 // 65536
  float* az  = q;
  float* u1  = q + MM * cBH;
  float* u2  = q + 2 * MM * cBH;
  float* t3p = q;                                // [bh][8][64][256] over az+u1
  float* zp[2] = {kbuf, kbuf + MM * cBH};
  float* zt[2] = {kbuf + 2 * MM * cBH, kbuf + 3 * MM * cBH};
  float* outh = vT;

  // weight transposes (once per call)
  trans_k<<<dim3(1536 / 32, 512 / 32, 1), 256, 0, stream>>>(w_qkv, wqT, 512, 1536, 0, 0);
  trans_k<<<dim3(512 / 32, 512 / 32, 1), 256, 0, stream>>>(w_out, woT, 512, 512, 0, 0);

  // 1) qkv = x @ w_qkv^T^T  -> NT(x, wqT)
  mfma_nt_k<128, 128, 2, 2><<<dim3(12, 64, 1), 256, 0, stream>>>(
      x, wqT, qkv, nullptr, nullptr,
      512, 512, 512, 1536, 0,
      0, 0, 0, 0, 0, 1, 0, 0, 0, 1.f, 0.f, nullptr);

  // 2) split
  qkv_split_k<<<(cBH * cN * cD) / 256, 256, 0, stream>>>(qkv, q, kbuf, v);

  // v^T for t3'-gemm
  trans_k<<<dim3(2, 128, cBH), 256, 0, stream>>>(v, vT, cN, cD, (long)cN * cD, (long)cN * cD);

  // 3) landmarks
  land_k<<<(cBH * cM * cD) / 256, 256, 0, stream>>>(q, ql);
  land_k<<<(cBH * cM * cD) / 256, 256, 0, stream>>>(kbuf, kl);

  // 4) sim1 = NT(q, kl) -> attn1 [bh,4096,256]
  mfma_nt_k<128, 128, 2, 2><<<dim3(2, 32, cBH), 256, 0, stream>>>(
      q, kl, attn1, nullptr, nullptr,
      64, 64, 64, 256, 0,
      (long)cN * cD, (long)cM * cD, (long)cN * cM, 0, 0, 1, 0, 0, 0, 1.f, 0.f, nullptr);
  softmax_k<256><<<(cBH * cN) / 4, 256, 0, stream>>>(attn1);

  // 5) sim2 = NT(ql, kl) -> attn2 [bh,256,256]
  mfma_nt_k<64, 64, 2, 2><<<dim3(4, 4, cBH), 256, 0, stream>>>(
      ql, kl, attn2, nullptr, nullptr,
      64, 64, 64, 256, 0,
      (long)cM * cD, (long)cM * cD, MM, 0, 0, 1, 0, 0, 0, 1.f, 0.f, nullptr);
  softmax_k<256><<<(cBH * cM) / 4, 256, 0, stream>>>(attn2);

  // 6) sim3 = NT(ql, k) -> attn3 [bh,256,4096]
  mfma_nt_k<128, 128, 2, 2><<<dim3(32, 2, cBH), 256, 0, stream>>>(
      ql, kbuf, attn3, nullptr, nullptr,
      64, 64, 64, 4096, 0,
      (long)cM * cD, (long)cN * cD, (long)cM * cN, 0, 0, 1, 0, 0, 0, 1.f, 0.f, nullptr);
  softmax_k<4096><<<(cBH * cM) / 4, 256, 0, stream>>>(attn3);

  // 7) pinv in transposed space. z' = z^T tracked as zp, z as zt.
  pinv_prep_k<<<cBH, 256, 0, stream>>>(attn2, mx);
  pinv_init2_k<<<dim3(8, 8, cBH), 256, 0, stream>>>(attn2, mx, zp[0], zt[0]);

  int cur = 0;
  for (int it = 0; it < 6; ++it) {
    int nxt = cur ^ 1;
    // az' = z'@a'  = NT(z', attn2); write CT=az, C2 = 7I - az'
    mfma_nt_k<64, 64, 2, 2><<<dim3(4, 4, cBH), 256, 0, stream>>>(
        zp[cur], attn2, nullptr, az, u1,
        256, 256, 256, 256, 256,
        MM, MM, 0, MM, MM, 1, 0, 0, 0, 1.f, 7.f, nullptr);
    // u2' = 15I - u1'@az' = C2 of NT(u1, az)
    mfma_nt_k<64, 64, 2, 2><<<dim3(4, 4, cBH), 256, 0, stream>>>(
        u1, az, nullptr, nullptr, u2,
        256, 256, 256, 256, 0,
        MM, MM, 0, 0, MM, 1, 0, 0, 0, 1.f, 15.f, nullptr);
    // u3' = 13I - u2'@az' -> into u1
    mfma_nt_k<64, 64, 2, 2><<<dim3(4, 4, cBH), 256, 0, stream>>>(
        u2, az, nullptr, nullptr, u1,
        256, 256, 256, 256, 0,
        MM, MM, 0, 0, MM, 1, 0, 0, 0, 1.f, 13.f, nullptr);
    // z_next' = 0.25*u3'@z^T = NT(u1, zt_cur); write plain + transposed
    mfma_nt_k<64, 64, 2, 2><<<dim3(4, 4, cBH), 256, 0, stream>>>(
        u1, zt[cur], zp[nxt], zt[nxt], nullptr,
        256, 256, 256, 256, 256,
        MM, MM, MM, MM, 0, 1, 0, 0, 0, 0.25f, 0.f, nullptr);
    cur = nxt;
  }

  // 8) t3' = NT(v^T, attn3)  [64 x 256], split-K=8 over K=4096
  mfma_nt_k<64, 64, 2, 2><<<dim3(4, 1, cBH * 8), 256, 0, stream>>>(
      vT, attn3, t3p, nullptr, nullptr,
      512, 4096, 4096, 256, 0,
      (long)cD * cN, (long)cM * cN, (long)8 * cD * cM, 0, 0,
      8, 512, 512, (long)cD * cM, 1.f, 0.f, nullptr);
  reduce8_k<<<(cBH * cD * cM) / 256, 256, 0, stream>>>(t3p, t3t);

  // 9) t4' = t3'@z' = NT(t3', z)  [64 x 256]
  mfma_nt_k<64, 64, 2, 2><<<dim3(4, 1, cBH), 256, 0, stream>>>(
      t3t, zt[cur], t4t, nullptr, nullptr,
      256, 256, 256, 256, 0,
      (long)cD * cM, MM, (long)cD * cM, 0, 0, 1, 0, 0, 0, 1.f, 0.f, nullptr);

  // 10) outh = attn1@t4 = NT(attn1, t4')  [4096 x 64]
  mfma_nt_k<64, 64, 2, 2><<<dim3(1, 64, cBH), 256, 0, stream>>>(
      attn1, t4t, outh, nullptr, nullptr,
      256, 256, 256, 64, 0,
      (long)cN * cM, (long)cD * cM, (long)cN * cD, 0, 0, 1, 0, 0, 0, 1.f, 0.f, nullptr);

  // 11) grouped-conv residual into outh
  conv_k<<<dim3(cN / 4, cB), 256, 0, stream>>>(v, cw, outh);

  // 12) [B,H,N,D] -> [B,N,512]
  rows_k<<<(cB * cN * cDIM) / 256, 256, 0, stream>>>(outh, xo);

  // 13) out = NT(xo, woT) + b_out
  mfma_nt_k<128, 128, 2, 2><<<dim3(4, 64, 1), 256, 0, stream>>>(
      xo, woT, out, nullptr, nullptr,
      512, 512, 512, 512, 0,
      0, 0, 0, 0, 0, 1, 0, 0, 0, 1.f, 0.f, b_out);
}